// Round 1
// baseline (230.286 us; speedup 1.0000x reference)
//
#include <hip/hip_runtime.h>
#include <cstdint>

#define NSTARS 4096
#define NDIC   4096
#define NFEAT  16
#define NPIX   65536    // 256*256
#define BATCH  2048

// ---------------------------------------------------------------------------
// Kernel A: fused index lookup + inter = spatial_dic[idx] @ alpha  -> d_ws
// One block handles 4 batch elements. 512 blocks x 256 threads.
// Lookup semantics faithful to reference: first flat-equal element in
// row-major [n_stars, 2] -> min star s with (x match OR y match); no match -> 0.
// ---------------------------------------------------------------------------
__global__ __launch_bounds__(256) void k_inter(
    const float*  __restrict__ positions,   // [BATCH,2]
    const float2* __restrict__ obs,         // [NSTARS] as float2
    const float*  __restrict__ spatial,     // [NSTARS,NDIC]
    const float*  __restrict__ alpha,       // [NDIC,NFEAT]
    float*        __restrict__ inter)       // [BATCH,NFEAT] out
{
    __shared__ int   s_idx[4];
    __shared__ float s_red[4 * 64];         // 4 waves x 64 (b,f) partials

    const int tid = threadIdx.x;
    const int b0  = blockIdx.x * 4;

    if (tid < 4) s_idx[tid] = 0x7FFFFFFF;
    __syncthreads();

    float px[4], py[4];
    #pragma unroll
    for (int b = 0; b < 4; ++b) {
        px[b] = positions[(b0 + b) * 2 + 0];
        py[b] = positions[(b0 + b) * 2 + 1];
    }

    for (int s = tid; s < NSTARS; s += 256) {
        float2 o = obs[s];
        #pragma unroll
        for (int b = 0; b < 4; ++b) {
            if (px[b] == o.x || py[b] == o.y) atomicMin(&s_idx[b], s);
        }
    }
    __syncthreads();

    int idx[4];
    #pragma unroll
    for (int b = 0; b < 4; ++b) {
        int v = s_idx[b];
        idx[b] = (v == 0x7FFFFFFF) ? 0 : v;
    }

    // inter accumulation: each thread covers 4 consecutive d per step,
    // 4 steps of 1024 -> all 4096 dictionary entries.
    float acc[4][NFEAT];
    #pragma unroll
    for (int b = 0; b < 4; ++b)
        #pragma unroll
        for (int f = 0; f < NFEAT; ++f) acc[b][f] = 0.0f;

    const float4* alpha4 = (const float4*)alpha;

    #pragma unroll
    for (int step = 0; step < 4; ++step) {
        const int d0 = tid * 4 + step * 1024;
        float4 v[4];
        #pragma unroll
        for (int b = 0; b < 4; ++b)
            v[b] = *(const float4*)(spatial + (size_t)idx[b] * NDIC + d0);

        #pragma unroll
        for (int k = 0; k < 4; ++k) {
            const float4 a0 = alpha4[(size_t)(d0 + k) * 4 + 0];
            const float4 a1 = alpha4[(size_t)(d0 + k) * 4 + 1];
            const float4 a2 = alpha4[(size_t)(d0 + k) * 4 + 2];
            const float4 a3 = alpha4[(size_t)(d0 + k) * 4 + 3];
            #pragma unroll
            for (int b = 0; b < 4; ++b) {
                const float vb = (&v[b].x)[k];
                acc[b][0]  += vb * a0.x;  acc[b][1]  += vb * a0.y;
                acc[b][2]  += vb * a0.z;  acc[b][3]  += vb * a0.w;
                acc[b][4]  += vb * a1.x;  acc[b][5]  += vb * a1.y;
                acc[b][6]  += vb * a1.z;  acc[b][7]  += vb * a1.w;
                acc[b][8]  += vb * a2.x;  acc[b][9]  += vb * a2.y;
                acc[b][10] += vb * a2.z;  acc[b][11] += vb * a2.w;
                acc[b][12] += vb * a3.x;  acc[b][13] += vb * a3.y;
                acc[b][14] += vb * a3.z;  acc[b][15] += vb * a3.w;
            }
        }
    }

    // wave-level butterfly reduce all 64 (b,f) partials
    #pragma unroll
    for (int b = 0; b < 4; ++b)
        #pragma unroll
        for (int f = 0; f < NFEAT; ++f) {
            float x = acc[b][f];
            #pragma unroll
            for (int off = 32; off > 0; off >>= 1)
                x += __shfl_down(x, off);
            acc[b][f] = x;
        }

    const int lane = tid & 63;
    const int wave = tid >> 6;
    if (lane == 0) {
        #pragma unroll
        for (int b = 0; b < 4; ++b)
            #pragma unroll
            for (int f = 0; f < NFEAT; ++f)
                s_red[wave * 64 + b * NFEAT + f] = acc[b][f];
    }
    __syncthreads();

    if (tid < 64) {
        const int b = tid >> 4, f = tid & 15;
        float x = s_red[0 * 64 + tid] + s_red[1 * 64 + tid]
                + s_red[2 * 64 + tid] + s_red[3 * 64 + tid];
        inter[(size_t)(b0 + b) * NFEAT + f] = x;
    }
}

// ---------------------------------------------------------------------------
// Kernel B: out[b, pix] = sum_f inter[b,f] * S[f, pix]
// Thread holds 16 float4 S-values in registers, reuses across 16 batch rows.
// Grid: 64 pixel-chunks (1024 px each) x 128 batch-groups (16 b each) = 8192.
// ---------------------------------------------------------------------------
__global__ __launch_bounds__(256) void k_opd(
    const float*  __restrict__ inter,   // [BATCH,NFEAT]
    const float4* __restrict__ S4,      // [NFEAT, NPIX/4]
    float4*       __restrict__ out4)    // [BATCH, NPIX/4]
{
    const int tid   = threadIdx.x;
    const int chunk = blockIdx.x & 63;       // pixel chunk
    const int bg    = blockIdx.x >> 6;       // batch group
    const int p4    = chunk * 256 + tid;     // float4 index in [0, 16384)

    float4 s[NFEAT];
    #pragma unroll
    for (int f = 0; f < NFEAT; ++f)
        s[f] = S4[(size_t)f * (NPIX / 4) + p4];

    #pragma unroll 4
    for (int b = 0; b < 16; ++b) {
        const int bi = bg * 16 + b;
        const float* __restrict__ w = inter + (size_t)bi * NFEAT;
        float4 acc = {0.f, 0.f, 0.f, 0.f};
        #pragma unroll
        for (int f = 0; f < NFEAT; ++f) {
            const float wf = w[f];
            acc.x += wf * s[f].x;
            acc.y += wf * s[f].y;
            acc.z += wf * s[f].z;
            acc.w += wf * s[f].w;
        }
        out4[(size_t)bi * (NPIX / 4) + p4] = acc;
    }
}

extern "C" void kernel_launch(void* const* d_in, const int* in_sizes, int n_in,
                              void* d_out, int out_size, void* d_ws, size_t ws_size,
                              hipStream_t stream) {
    const float*  positions = (const float*)d_in[0];   // [2048,2]
    const float2* obs       = (const float2*)d_in[1];  // [4096,2]
    const float*  spatial   = (const float*)d_in[2];   // [4096,4096]
    const float*  alpha     = (const float*)d_in[3];   // [4096,16]
    const float4* S4        = (const float4*)d_in[4];  // [16,256,256]
    float*        out       = (float*)d_out;           // [2048,256,256]
    float*        inter     = (float*)d_ws;            // [2048,16] scratch

    k_inter<<<BATCH / 4, 256, 0, stream>>>(positions, obs, spatial, alpha, inter);
    k_opd<<<(NPIX / 1024) * (BATCH / 16), 256, 0, stream>>>(inter, S4, (float4*)out);
}

// Round 2
// 145.987 us; speedup vs baseline: 1.5774x; 1.5774x over previous
//
#include <hip/hip_runtime.h>
#include <cstdint>

#define NSTARS 4096
#define NDIC   4096
#define NFEAT  16
#define NPIX   65536    // 256*256
#define BATCH  2048
#define BPB    128      // batch rows per k_opd block

using f32x4 = __attribute__((ext_vector_type(4))) float;

// ---------------------------------------------------------------------------
// Kernel A: fused index lookup + inter = spatial_dic[idx] @ alpha  -> d_ws
// (unchanged from R1 — control variable this round)
// ---------------------------------------------------------------------------
__global__ __launch_bounds__(256) void k_inter(
    const float*  __restrict__ positions,   // [BATCH,2]
    const float2* __restrict__ obs,         // [NSTARS] as float2
    const float*  __restrict__ spatial,     // [NSTARS,NDIC]
    const float*  __restrict__ alpha,       // [NDIC,NFEAT]
    float*        __restrict__ inter)       // [BATCH,NFEAT] out
{
    __shared__ int   s_idx[4];
    __shared__ float s_red[4 * 64];

    const int tid = threadIdx.x;
    const int b0  = blockIdx.x * 4;

    if (tid < 4) s_idx[tid] = 0x7FFFFFFF;
    __syncthreads();

    float px[4], py[4];
    #pragma unroll
    for (int b = 0; b < 4; ++b) {
        px[b] = positions[(b0 + b) * 2 + 0];
        py[b] = positions[(b0 + b) * 2 + 1];
    }

    for (int s = tid; s < NSTARS; s += 256) {
        float2 o = obs[s];
        #pragma unroll
        for (int b = 0; b < 4; ++b) {
            if (px[b] == o.x || py[b] == o.y) atomicMin(&s_idx[b], s);
        }
    }
    __syncthreads();

    int idx[4];
    #pragma unroll
    for (int b = 0; b < 4; ++b) {
        int v = s_idx[b];
        idx[b] = (v == 0x7FFFFFFF) ? 0 : v;
    }

    float acc[4][NFEAT];
    #pragma unroll
    for (int b = 0; b < 4; ++b)
        #pragma unroll
        for (int f = 0; f < NFEAT; ++f) acc[b][f] = 0.0f;

    const float4* alpha4 = (const float4*)alpha;

    #pragma unroll
    for (int step = 0; step < 4; ++step) {
        const int d0 = tid * 4 + step * 1024;
        float4 v[4];
        #pragma unroll
        for (int b = 0; b < 4; ++b)
            v[b] = *(const float4*)(spatial + (size_t)idx[b] * NDIC + d0);

        #pragma unroll
        for (int k = 0; k < 4; ++k) {
            const float4 a0 = alpha4[(size_t)(d0 + k) * 4 + 0];
            const float4 a1 = alpha4[(size_t)(d0 + k) * 4 + 1];
            const float4 a2 = alpha4[(size_t)(d0 + k) * 4 + 2];
            const float4 a3 = alpha4[(size_t)(d0 + k) * 4 + 3];
            #pragma unroll
            for (int b = 0; b < 4; ++b) {
                const float vb = (&v[b].x)[k];
                acc[b][0]  += vb * a0.x;  acc[b][1]  += vb * a0.y;
                acc[b][2]  += vb * a0.z;  acc[b][3]  += vb * a0.w;
                acc[b][4]  += vb * a1.x;  acc[b][5]  += vb * a1.y;
                acc[b][6]  += vb * a1.z;  acc[b][7]  += vb * a1.w;
                acc[b][8]  += vb * a2.x;  acc[b][9]  += vb * a2.y;
                acc[b][10] += vb * a2.z;  acc[b][11] += vb * a2.w;
                acc[b][12] += vb * a3.x;  acc[b][13] += vb * a3.y;
                acc[b][14] += vb * a3.z;  acc[b][15] += vb * a3.w;
            }
        }
    }

    #pragma unroll
    for (int b = 0; b < 4; ++b)
        #pragma unroll
        for (int f = 0; f < NFEAT; ++f) {
            float x = acc[b][f];
            #pragma unroll
            for (int off = 32; off > 0; off >>= 1)
                x += __shfl_down(x, off);
            acc[b][f] = x;
        }

    const int lane = tid & 63;
    const int wave = tid >> 6;
    if (lane == 0) {
        #pragma unroll
        for (int b = 0; b < 4; ++b)
            #pragma unroll
            for (int f = 0; f < NFEAT; ++f)
                s_red[wave * 64 + b * NFEAT + f] = acc[b][f];
    }
    __syncthreads();

    if (tid < 64) {
        const int b = tid >> 4, f = tid & 15;
        float x = s_red[0 * 64 + tid] + s_red[1 * 64 + tid]
                + s_red[2 * 64 + tid] + s_red[3 * 64 + tid];
        inter[(size_t)(b0 + b) * NFEAT + f] = x;
    }
}

// ---------------------------------------------------------------------------
// Kernel B v2: out[b, pix] = sum_f inter[b,f] * S[f, pix]
// 128 batch rows per block (8x more S-register reuse), nontemporal stores so
// the 512 MiB write stream does not evict S from the per-XCD L2.
// Grid: 64 pixel-chunks x 16 batch-groups = 1024 blocks (chunk%8 == XCD).
// ---------------------------------------------------------------------------
__global__ __launch_bounds__(256) void k_opd(
    const float4* __restrict__ inter4,  // [BATCH, 4] float4 rows
    const f32x4*  __restrict__ S4,      // [NFEAT, NPIX/4]
    f32x4*        __restrict__ out4)    // [BATCH, NPIX/4]
{
    const int tid   = threadIdx.x;
    const int chunk = blockIdx.x & 63;       // pixel chunk (1024 px)
    const int bg    = blockIdx.x >> 6;       // batch group of BPB rows
    const int p4    = chunk * 256 + tid;     // float4 index in [0, 16384)

    f32x4 s[NFEAT];
    #pragma unroll
    for (int f = 0; f < NFEAT; ++f)
        s[f] = S4[(size_t)f * (NPIX / 4) + p4];

    const float4* w4 = inter4 + (size_t)bg * BPB * 4;
    f32x4* o = out4 + (size_t)bg * BPB * (NPIX / 4) + p4;

    #pragma unroll 2
    for (int b = 0; b < BPB; ++b) {
        const float4 wa = w4[b * 4 + 0];
        const float4 wb = w4[b * 4 + 1];
        const float4 wc = w4[b * 4 + 2];
        const float4 wd = w4[b * 4 + 3];

        f32x4 acc = s[0] * wa.x;
        acc += s[1]  * wa.y;  acc += s[2]  * wa.z;  acc += s[3]  * wa.w;
        acc += s[4]  * wb.x;  acc += s[5]  * wb.y;  acc += s[6]  * wb.z;
        acc += s[7]  * wb.w;  acc += s[8]  * wc.x;  acc += s[9]  * wc.y;
        acc += s[10] * wc.z;  acc += s[11] * wc.w;  acc += s[12] * wd.x;
        acc += s[13] * wd.y;  acc += s[14] * wd.z;  acc += s[15] * wd.w;

        __builtin_nontemporal_store(acc, o + (size_t)b * (NPIX / 4));
    }
}

extern "C" void kernel_launch(void* const* d_in, const int* in_sizes, int n_in,
                              void* d_out, int out_size, void* d_ws, size_t ws_size,
                              hipStream_t stream) {
    const float*  positions = (const float*)d_in[0];   // [2048,2]
    const float2* obs       = (const float2*)d_in[1];  // [4096,2]
    const float*  spatial   = (const float*)d_in[2];   // [4096,4096]
    const float*  alpha     = (const float*)d_in[3];   // [4096,16]
    const f32x4*  S4        = (const f32x4*)d_in[4];   // [16,256,256]
    f32x4*        out       = (f32x4*)d_out;           // [2048,256,256]
    float*        inter     = (float*)d_ws;            // [2048,16] scratch

    k_inter<<<BATCH / 4, 256, 0, stream>>>(positions, obs, spatial, alpha, inter);
    k_opd<<<(NPIX / 1024) * (BATCH / BPB), 256, 0, stream>>>(
        (const float4*)inter, S4, out);
}